// Round 1
// baseline (177.421 us; speedup 1.0000x reference)
//
#include <hip/hip_runtime.h>

// Problem constants (match reference file)
#define B_DIM 512
#define S_DIM 1024
#define NTOK (B_DIM * S_DIM)          // 524288 tokens
#define CHAR_LEN 32
#define MAX_CANDS 4000
#define N_PRIV 8
#define CTX_RATE 0.15f

// Output layout (concatenated flat, int32):
//   [0*NTOK)            obf_word
//   [1*NTOK)            inp_word (copy)
//   [2*NTOK)            obf_char (NTOK*32)
//   [34*NTOK)           inp_pos (copy)
//   [35*NTOK)           obf_mask (0/1)
//   [36*NTOK)           pri_mask (0/1)
//   [37*NTOK)           cpy_mask (0/1)
// total = 38*NTOK = 19922944

__global__ __launch_bounds__(256) void alltag_kernel(
    const int* __restrict__ inp_word,
    const int* __restrict__ inp_pos,
    const int* __restrict__ inp_mask,
    const float* __restrict__ ctx_rand,
    const float* __restrict__ pri_rand,
    const float* __restrict__ cand_u,
    const int4* __restrict__ lut4,       // [VOCAB][8] int4 (= [VOCAB][32] int)
    const int* __restrict__ tgt_table,   // [N_POS][MAX_CANDS]
    const int* __restrict__ counts,      // [N_POS]
    int* __restrict__ out)
{
    int t = blockIdx.x * blockDim.x + threadIdx.x;   // int4-granular work item
    if (t >= NTOK * 8) return;
    int token = t >> 3;       // 8 int4 chunks per token's 32-char row
    int sub   = t & 7;

    int pos  = inp_pos[token];
    int word = inp_word[token];
    bool pri_mask = (pos < N_PRIV);   // priv_pos = arange(N_POS) < N_PRIV

    bool obf;
    if (pri_mask) obf = (pri_rand[token] < 1.0f);
    else          obf = (ctx_rand[token] < CTX_RATE);

    int obf_word = word;
    if (obf) {
        int cnt = counts[pos];
        // JAX: min((cand_u * float(cnt)) truncated to int32, cnt-1)
        int idx = (int)(cand_u[token] * (float)cnt);
        idx = min(idx, cnt - 1);
        obf_word = tgt_table[pos * MAX_CANDS + idx];
    }

    // char gather: lut row (128B) copied as 8 x int4, lane-contiguous stores
    int4 v = lut4[obf_word * 8 + sub];
    int4* out_char4 = (int4*)(out + (size_t)NTOK * 2);
    out_char4[(size_t)token * 8 + sub] = v;

    if (sub == 0) {
        out[token]                      = obf_word;
        out[NTOK + token]               = word;
        out[(size_t)NTOK * 34 + token]  = pos;
        out[(size_t)NTOK * 35 + token]  = obf ? 1 : 0;
        out[(size_t)NTOK * 36 + token]  = pri_mask ? 1 : 0;
        bool cpy = (inp_mask[token] != 0) && (word == obf_word);
        out[(size_t)NTOK * 37 + token]  = cpy ? 1 : 0;
    }
}

extern "C" void kernel_launch(void* const* d_in, const int* in_sizes, int n_in,
                              void* d_out, int out_size, void* d_ws, size_t ws_size,
                              hipStream_t stream) {
    // setup_inputs() order:
    // 0 inp_word [B,S] i32, 1 inp_char [B,S,32] i32 (unused), 2 inp_pos [B,S] i32,
    // 3 inp_mask [B,S] i32, 4 ctx_rand [B,S] f32, 5 pri_rand [B,S] f32,
    // 6 cand_u [B,S] f32, 7 lut [VOCAB,32] i32, 8 tgt_table [40,4000] i32,
    // 9 counts [40] i32, 10 priv_pos [40] bool (unused; == arange<8)
    const int*   inp_word  = (const int*)  d_in[0];
    const int*   inp_pos   = (const int*)  d_in[2];
    const int*   inp_mask  = (const int*)  d_in[3];
    const float* ctx_rand  = (const float*)d_in[4];
    const float* pri_rand  = (const float*)d_in[5];
    const float* cand_u    = (const float*)d_in[6];
    const int4*  lut4      = (const int4*) d_in[7];
    const int*   tgt_table = (const int*)  d_in[8];
    const int*   counts    = (const int*)  d_in[9];
    int* out = (int*)d_out;

    const int total = NTOK * 8;               // 4194304 int4 work items
    const int block = 256;
    const int grid  = (total + block - 1) / block;  // 16384
    alltag_kernel<<<grid, block, 0, stream>>>(inp_word, inp_pos, inp_mask,
                                              ctx_rand, pri_rand, cand_u,
                                              lut4, tgt_table, counts, out);
}

// Round 3
// 172.742 us; speedup vs baseline: 1.0271x; 1.0271x over previous
//
#include <hip/hip_runtime.h>

// Problem constants (match reference file)
#define B_DIM 512
#define S_DIM 1024
#define NTOK (B_DIM * S_DIM)          // 524288 tokens
#define CHAR_LEN 32
#define MAX_CANDS 4000
#define N_PRIV 8
#define CTX_RATE 0.15f

typedef int vint4 __attribute__((ext_vector_type(4)));  // clang-native 16B vector

// Output layout (concatenated flat, int32):
//   [0*NTOK)   obf_word
//   [1*NTOK)   inp_word (copy)
//   [2*NTOK)   obf_char (NTOK*32)
//   [34*NTOK)  inp_pos (copy)
//   [35*NTOK)  obf_mask (0/1)
//   [36*NTOK)  pri_mask (0/1)
//   [37*NTOK)  cpy_mask (0/1)

__device__ __forceinline__ void do_token(
    int token, int sub,
    const int* __restrict__ inp_word,
    const int* __restrict__ inp_pos,
    const int* __restrict__ inp_mask,
    const float* __restrict__ ctx_rand,
    const float* __restrict__ pri_rand,
    const float* __restrict__ cand_u,
    const vint4* __restrict__ lut4,
    const int* __restrict__ tgt_table,
    const int* __restrict__ counts,
    int* __restrict__ out)
{
    int pos   = __builtin_nontemporal_load(&inp_pos[token]);
    int word  = __builtin_nontemporal_load(&inp_word[token]);
    float cr  = __builtin_nontemporal_load(&ctx_rand[token]);
    float pr  = __builtin_nontemporal_load(&pri_rand[token]);
    float cu  = __builtin_nontemporal_load(&cand_u[token]);

    bool pri_mask = (pos < N_PRIV);                 // priv_pos = arange < N_PRIV
    bool obf = pri_mask ? (pr < 1.0f) : (cr < CTX_RATE);

    // branchless candidate gather (tgt_table is 640 KB -> L2-resident)
    int cnt = counts[pos];
    int idx = (int)(cu * (float)cnt);               // JAX trunc semantics
    idx = min(idx, cnt - 1);
    int cdt = tgt_table[pos * MAX_CANDS + idx];
    int obf_word = obf ? cdt : word;

    // char gather: lut row (128B) as 8 x vint4, lane-contiguous stores
    vint4 v = lut4[obf_word * 8 + sub];             // keep cached (lut reuse)
    vint4* out_char4 = (vint4*)(out + (size_t)NTOK * 2);
    __builtin_nontemporal_store(v, &out_char4[(size_t)token * 8 + sub]);

    if (sub == 0) {
        __builtin_nontemporal_store(obf_word, &out[token]);
        __builtin_nontemporal_store(word, &out[NTOK + token]);
        __builtin_nontemporal_store(pos, &out[(size_t)NTOK * 34 + token]);
        __builtin_nontemporal_store(obf ? 1 : 0, &out[(size_t)NTOK * 35 + token]);
        __builtin_nontemporal_store(pri_mask ? 1 : 0, &out[(size_t)NTOK * 36 + token]);
        int msk = __builtin_nontemporal_load(&inp_mask[token]);
        bool cpy = (msk != 0) && (word == obf_word);
        __builtin_nontemporal_store(cpy ? 1 : 0, &out[(size_t)NTOK * 37 + token]);
    }
}

__global__ __launch_bounds__(256) void alltag_kernel(
    const int* __restrict__ inp_word,
    const int* __restrict__ inp_pos,
    const int* __restrict__ inp_mask,
    const float* __restrict__ ctx_rand,
    const float* __restrict__ pri_rand,
    const float* __restrict__ cand_u,
    const vint4* __restrict__ lut4,
    const int* __restrict__ tgt_table,
    const int* __restrict__ counts,
    int* __restrict__ out)
{
    int g = blockIdx.x * blockDim.x + threadIdx.x;   // [0, NTOK*4)
    int token0 = g >> 3;                             // [0, NTOK/2)
    int sub    = g & 7;
    int token1 = token0 + (NTOK / 2);

    // two independent chains per thread -> 2x memory-level parallelism
    do_token(token0, sub, inp_word, inp_pos, inp_mask, ctx_rand, pri_rand,
             cand_u, lut4, tgt_table, counts, out);
    do_token(token1, sub, inp_word, inp_pos, inp_mask, ctx_rand, pri_rand,
             cand_u, lut4, tgt_table, counts, out);
}

extern "C" void kernel_launch(void* const* d_in, const int* in_sizes, int n_in,
                              void* d_out, int out_size, void* d_ws, size_t ws_size,
                              hipStream_t stream) {
    const int*   inp_word  = (const int*)  d_in[0];
    const int*   inp_pos   = (const int*)  d_in[2];
    const int*   inp_mask  = (const int*)  d_in[3];
    const float* ctx_rand  = (const float*)d_in[4];
    const float* pri_rand  = (const float*)d_in[5];
    const float* cand_u    = (const float*)d_in[6];
    const vint4* lut4      = (const vint4*)d_in[7];
    const int*   tgt_table = (const int*)  d_in[8];
    const int*   counts    = (const int*)  d_in[9];
    int* out = (int*)d_out;

    const int total = NTOK * 4;               // 2 tokens per 8-lane group
    const int block = 256;
    const int grid  = (total + block - 1) / block;  // 8192
    alltag_kernel<<<grid, block, 0, stream>>>(inp_word, inp_pos, inp_mask,
                                              ctx_rand, pri_rand, cand_u,
                                              lut4, tgt_table, counts, out);
}

// Round 4
// 159.277 us; speedup vs baseline: 1.1139x; 1.0845x over previous
//
#include <hip/hip_runtime.h>

// Problem constants (match reference file)
#define B_DIM 512
#define S_DIM 1024
#define NTOK (B_DIM * S_DIM)          // 524288 tokens
#define CHAR_LEN 32
#define MAX_CANDS 4000
#define N_PRIV 8
#define CTX_RATE 0.15f

typedef int vint4 __attribute__((ext_vector_type(4)));  // clang-native 16B vector

// Output layout (concatenated flat, int32):
//   [0*NTOK)   obf_word
//   [1*NTOK)   inp_word (copy)
//   [2*NTOK)   obf_char (NTOK*32)
//   [34*NTOK)  inp_pos (copy)
//   [35*NTOK)  obf_mask (0/1)
//   [36*NTOK)  pri_mask (0/1)
//   [37*NTOK)  cpy_mask (0/1)

__global__ __launch_bounds__(256) void alltag_kernel(
    const int* __restrict__ inp_word,
    const int* __restrict__ inp_pos,
    const int* __restrict__ inp_mask,
    const float* __restrict__ ctx_rand,
    const float* __restrict__ pri_rand,
    const float* __restrict__ cand_u,
    const vint4* __restrict__ lut4,      // [VOCAB][8] vint4
    const int* __restrict__ tgt_table,   // [N_POS][MAX_CANDS]
    const int* __restrict__ counts,      // [N_POS]
    int* __restrict__ out)
{
    __shared__ int s_obf_word[256];

    const int tid        = threadIdx.x;
    const int token_base = blockIdx.x * 256;

    // ---------------- Phase A: 1 thread = 1 token (coalesced scalars) ------
    {
        const int token = token_base + tid;
        int   pos  = __builtin_nontemporal_load(&inp_pos[token]);
        int   word = __builtin_nontemporal_load(&inp_word[token]);
        float cr   = __builtin_nontemporal_load(&ctx_rand[token]);
        float pr   = __builtin_nontemporal_load(&pri_rand[token]);
        float cu   = __builtin_nontemporal_load(&cand_u[token]);
        int   msk  = __builtin_nontemporal_load(&inp_mask[token]);

        bool pri_mask = (pos < N_PRIV);              // priv_pos = arange < N_PRIV
        bool obf = pri_mask ? (pr < 1.0f) : (cr < CTX_RATE);

        int cnt = counts[pos];                       // 160B, L1-resident
        int idx = (int)(cu * (float)cnt);            // JAX trunc semantics
        idx = min(idx, cnt - 1);
        int cdt = tgt_table[pos * MAX_CANDS + idx];  // 640KB, L2-resident
        int obf_word = obf ? cdt : word;

        s_obf_word[tid] = obf_word;

        __builtin_nontemporal_store(obf_word, &out[token]);
        __builtin_nontemporal_store(word, &out[NTOK + token]);
        __builtin_nontemporal_store(pos, &out[(size_t)NTOK * 34 + token]);
        __builtin_nontemporal_store(obf ? 1 : 0, &out[(size_t)NTOK * 35 + token]);
        __builtin_nontemporal_store(pri_mask ? 1 : 0, &out[(size_t)NTOK * 36 + token]);
        bool cpy = (msk != 0) && (word == obf_word);
        __builtin_nontemporal_store(cpy ? 1 : 0, &out[(size_t)NTOK * 37 + token]);
    }

    __syncthreads();

    // ---------------- Phase B: 8 lanes/token, 8 independent gathers --------
    {
        const int sub   = tid & 7;       // which 16B chunk of the 128B row
        const int group = tid >> 3;      // [0,32): token group within block
        vint4* out_char4 = (vint4*)(out + (size_t)NTOK * 2);

#pragma unroll
        for (int i = 0; i < 8; ++i) {
            int lt = group + 32 * i;                  // local token [0,256)
            int w  = s_obf_word[lt];                  // LDS broadcast (free)
            vint4 v = lut4[w * 8 + sub];              // random 16B gather
            __builtin_nontemporal_store(
                v, &out_char4[(size_t)(token_base + lt) * 8 + sub]);
        }
    }
}

extern "C" void kernel_launch(void* const* d_in, const int* in_sizes, int n_in,
                              void* d_out, int out_size, void* d_ws, size_t ws_size,
                              hipStream_t stream) {
    const int*   inp_word  = (const int*)  d_in[0];
    const int*   inp_pos   = (const int*)  d_in[2];
    const int*   inp_mask  = (const int*)  d_in[3];
    const float* ctx_rand  = (const float*)d_in[4];
    const float* pri_rand  = (const float*)d_in[5];
    const float* cand_u    = (const float*)d_in[6];
    const vint4* lut4      = (const vint4*)d_in[7];
    const int*   tgt_table = (const int*)  d_in[8];
    const int*   counts    = (const int*)  d_in[9];
    int* out = (int*)d_out;

    const int block = 256;
    const int grid  = NTOK / block;          // 2048 blocks = 8192 waves
    alltag_kernel<<<grid, block, 0, stream>>>(inp_word, inp_pos, inp_mask,
                                              ctx_rand, pri_rand, cand_u,
                                              lut4, tgt_table, counts, out);
}